// Round 1
// baseline (530.513 us; speedup 1.0000x reference)
//
#include <hip/hip_runtime.h>
#include <hip/hip_bf16.h>

#define BATCH 4
#define SEQ   4096
#define DIN   512
#define DOUT  64

typedef __attribute__((ext_vector_type(4))) float f32x4;
typedef __attribute__((ext_vector_type(8))) short bf16x8;   // 8 bf16 = 4 VGPRs

__device__ __forceinline__ f32x4 mfma16(bf16x8 a, bf16x8 b, f32x4 c) {
    return __builtin_amdgcn_mfma_f32_16x16x32_bf16(a, b, c, 0, 0, 0);
}

// fp32 -> bf16 round-to-nearest-even (finite inputs only)
__device__ __forceinline__ short f2bf(float f) {
    union { float f; unsigned u; } x; x.f = f;
    unsigned r = x.u + 0x7FFFu + ((x.u >> 16) & 1u);
    return (short)(r >> 16);
}

// ---------------------------------------------------------------------------
// QKV projection: [B*S, 512] x [512, 64] -> bf16.
// m = blockIdx.y: 0 -> Q (row-major), 1 -> K (row-major), 2 -> V (transposed
// as Vt[b][e][s] so PV B-fragments are contiguous 16B loads).
// Each block: 16 rows; each wave: 4 rows x 64 cols (lane = col).
// ---------------------------------------------------------------------------
__global__ __launch_bounds__(256) void proj_kernel(
    const float* __restrict__ Xq, const float* __restrict__ Xk, const float* __restrict__ Xv,
    const float* __restrict__ Wq, const float* __restrict__ Wk, const float* __restrict__ Wv,
    short* __restrict__ Qb, short* __restrict__ Kb, short* __restrict__ Vt)
{
    const int m = blockIdx.y;
    const float* X = (m == 0) ? Xq : (m == 1) ? Xk : Xv;
    const float* W = (m == 0) ? Wq : (m == 1) ? Wk : Wv;

    const int tid = threadIdx.x;
    const int col = tid & 63;
    const int wv  = tid >> 6;
    const long row0 = (long)blockIdx.x * 16 + wv * 4;

    const float* x0 = X + row0 * DIN;
    float acc0 = 0.f, acc1 = 0.f, acc2 = 0.f, acc3 = 0.f;

    #pragma unroll 4
    for (int k = 0; k < DIN; k += 4) {
        float4 a0 = *(const float4*)(x0 + k);
        float4 a1 = *(const float4*)(x0 + DIN + k);
        float4 a2 = *(const float4*)(x0 + 2 * DIN + k);
        float4 a3 = *(const float4*)(x0 + 3 * DIN + k);
        float w0 = W[(k + 0) * DOUT + col];
        float w1 = W[(k + 1) * DOUT + col];
        float w2 = W[(k + 2) * DOUT + col];
        float w3 = W[(k + 3) * DOUT + col];
        acc0 += a0.x * w0 + a0.y * w1 + a0.z * w2 + a0.w * w3;
        acc1 += a1.x * w0 + a1.y * w1 + a1.z * w2 + a1.w * w3;
        acc2 += a2.x * w0 + a2.y * w1 + a2.z * w2 + a2.w * w3;
        acc3 += a3.x * w0 + a3.y * w1 + a3.z * w2 + a3.w * w3;
    }

    if (m < 2) {
        short* O = (m == 0) ? Qb : Kb;
        O[(row0 + 0) * DOUT + col] = f2bf(acc0);
        O[(row0 + 1) * DOUT + col] = f2bf(acc1);
        O[(row0 + 2) * DOUT + col] = f2bf(acc2);
        O[(row0 + 3) * DOUT + col] = f2bf(acc3);
    } else {
        const long b = row0 >> 12;            // row0 / SEQ
        const long s = row0 & (SEQ - 1);
        short* vp = Vt + (b * DOUT + col) * SEQ + s;
        vp[0] = f2bf(acc0);
        vp[1] = f2bf(acc1);
        vp[2] = f2bf(acc2);
        vp[3] = f2bf(acc3);
    }
}

// ---------------------------------------------------------------------------
// Causal flash attention, bf16 MFMA 16x16x32.
// One wave per 16 q-rows; 4 independent waves per block (no inter-wave deps).
// Fragment layouts (verified m89):
//   A: A[m][k], m = lane&15, k = (lane>>4)*8 + j   (8 contiguous bf16 -> 16B load)
//   B: B[k][n], n = lane&15, k = (lane>>4)*8 + j   (contiguous in K row-major / Vt)
//   C: row = (lane>>4)*4 + reg, col = lane&15
// P (C layout) -> A layout via per-wave LDS roundtrip, fp32, padded stride 36.
// ---------------------------------------------------------------------------
__global__ __launch_bounds__(256) void flash_kernel(
    const short* __restrict__ Qb, const short* __restrict__ Kb,
    const short* __restrict__ Vt, float* __restrict__ Out)
{
    __shared__ float s_p[4][16][36];   // per-wave 16x32 P tile, stride 36 (16B-aligned rows)

    const int b    = blockIdx.y;
    const int tid  = threadIdx.x;
    const int wv   = tid >> 6;
    const int lane = tid & 63;
    const int quad = lane >> 4;
    const int l16  = lane & 15;
    const int q0   = blockIdx.x * 64 + wv * 16;

    const short* Qp = Qb + ((long)b * SEQ + q0 + l16) * DOUT + quad * 8;
    bf16x8 qf0 = *(const bf16x8*)(Qp);        // d = 0..31
    bf16x8 qf1 = *(const bf16x8*)(Qp + 32);   // d = 32..63

    const short* Kbase = Kb + (long)b * SEQ * DOUT;
    const short* Vbase = Vt + (long)b * DOUT * SEQ;

    f32x4 acc[4];
    #pragma unroll
    for (int e = 0; e < 4; ++e) acc[e] = (f32x4){0.f, 0.f, 0.f, 0.f};
    float mrow[4] = {-1e30f, -1e30f, -1e30f, -1e30f};
    float lrow[4] = {0.f, 0.f, 0.f, 0.f};

    const int q_hi = q0 + 15;
    float* lp = &s_p[wv][0][0];

    for (int s0 = 0; s0 <= q_hi; s0 += 32) {
        // ---- scores S = Q K^T for 16 q-rows x 32 keys ----
        f32x4 sc0 = (f32x4){0.f, 0.f, 0.f, 0.f};
        f32x4 sc1 = (f32x4){0.f, 0.f, 0.f, 0.f};
        {
            const short* kp0 = Kbase + (long)(s0 + l16) * DOUT + quad * 8;
            const short* kp1 = Kbase + (long)(s0 + 16 + l16) * DOUT + quad * 8;
            bf16x8 k00 = *(const bf16x8*)(kp0);
            bf16x8 k01 = *(const bf16x8*)(kp0 + 32);
            bf16x8 k10 = *(const bf16x8*)(kp1);
            bf16x8 k11 = *(const bf16x8*)(kp1 + 32);
            sc0 = mfma16(qf0, k00, sc0);
            sc0 = mfma16(qf1, k01, sc0);
            sc1 = mfma16(qf0, k10, sc1);
            sc1 = mfma16(qf1, k11, sc1);
        }

        // ---- scale + causal mask (-1e30, never -inf => no NaN) ----
        #pragma unroll
        for (int r = 0; r < 4; ++r) {
            const int rowg = q0 + quad * 4 + r;
            sc0[r] = ((s0 + l16)      <= rowg) ? sc0[r] * 0.125f : -1e30f;
            sc1[r] = ((s0 + 16 + l16) <= rowg) ? sc1[r] * 0.125f : -1e30f;
        }

        // ---- online softmax: row max / exp / row sum (16-lane groups) ----
        float tm[4], alpha[4], p0[4], p1[4], rs[4];
        #pragma unroll
        for (int r = 0; r < 4; ++r) tm[r] = fmaxf(sc0[r], sc1[r]);
        #pragma unroll
        for (int off = 1; off < 16; off <<= 1) {
            #pragma unroll
            for (int r = 0; r < 4; ++r)
                tm[r] = fmaxf(tm[r], __shfl_xor(tm[r], off, 64));
        }
        #pragma unroll
        for (int r = 0; r < 4; ++r) {
            const float mn = fmaxf(mrow[r], tm[r]);   // finite after tile 0 (col 0 valid)
            alpha[r] = __expf(mrow[r] - mn);
            mrow[r]  = mn;
            p0[r] = __expf(sc0[r] - mn);
            p1[r] = __expf(sc1[r] - mn);
            rs[r] = p0[r] + p1[r];
        }
        #pragma unroll
        for (int off = 1; off < 16; off <<= 1) {
            #pragma unroll
            for (int r = 0; r < 4; ++r)
                rs[r] += __shfl_xor(rs[r], off, 64);
        }
        #pragma unroll
        for (int r = 0; r < 4; ++r) lrow[r] = lrow[r] * alpha[r] + rs[r];
        #pragma unroll
        for (int e = 0; e < 4; ++e)
            #pragma unroll
            for (int r = 0; r < 4; ++r) acc[e][r] *= alpha[r];

        // ---- P: C layout -> A layout via LDS (intra-wave; asm fences) ----
        __asm__ volatile("s_waitcnt lgkmcnt(0)" ::: "memory");  // WAR vs prev iter reads
        #pragma unroll
        for (int r = 0; r < 4; ++r) {
            lp[(quad * 4 + r) * 36 + l16]      = p0[r];
            lp[(quad * 4 + r) * 36 + 16 + l16] = p1[r];
        }
        __asm__ volatile("s_waitcnt lgkmcnt(0)" ::: "memory");  // RAW: writes visible
        const float* rp = lp + l16 * 36 + quad * 8;
        float4 pa = *(const float4*)(rp);
        float4 pb = *(const float4*)(rp + 4);
        bf16x8 pf;
        pf[0] = f2bf(pa.x); pf[1] = f2bf(pa.y); pf[2] = f2bf(pa.z); pf[3] = f2bf(pa.w);
        pf[4] = f2bf(pb.x); pf[5] = f2bf(pb.y); pf[6] = f2bf(pb.z); pf[7] = f2bf(pb.w);

        // ---- O += P V  (B-frag = contiguous 16B from Vt) ----
        #pragma unroll
        for (int e = 0; e < 4; ++e) {
            const short* vp = Vbase + (long)(e * 16 + l16) * SEQ + s0 + quad * 8;
            bf16x8 vf = *(const bf16x8*)(vp);
            acc[e] = mfma16(pf, vf, acc[e]);
        }
    }

    // ---- epilogue: O / l ----
    float invl[4];
    #pragma unroll
    for (int r = 0; r < 4; ++r) invl[r] = 1.0f / lrow[r];
    float* op = Out + ((long)b * SEQ + q0) * DOUT;
    #pragma unroll
    for (int e = 0; e < 4; ++e)
        #pragma unroll
        for (int r = 0; r < 4; ++r)
            op[(quad * 4 + r) * DOUT + e * 16 + l16] = acc[e][r] * invl[r];
}

extern "C" void kernel_launch(void* const* d_in, const int* in_sizes, int n_in,
                              void* d_out, int out_size, void* d_ws, size_t ws_size,
                              hipStream_t stream) {
    const float* key_in   = (const float*)d_in[0];
    const float* value_in = (const float*)d_in[1];
    const float* query_in = (const float*)d_in[2];
    const float* Wq = (const float*)d_in[3];
    const float* Wk = (const float*)d_in[4];
    const float* Wv = (const float*)d_in[5];
    float* out = (float*)d_out;

    short* Qb = (short*)d_ws;                          // 2 MB bf16 [B][S][64]
    short* Kb = Qb + (long)BATCH * SEQ * DOUT;         // 2 MB bf16 [B][S][64]
    short* Vt = Kb + (long)BATCH * SEQ * DOUT;         // 2 MB bf16 [B][64][S]

    dim3 pgrid(BATCH * SEQ / 16, 3);
    proj_kernel<<<pgrid, 256, 0, stream>>>(query_in, key_in, value_in,
                                           Wq, Wk, Wv, Qb, Kb, Vt);

    dim3 fgrid(SEQ / 64, BATCH);
    flash_kernel<<<fgrid, 256, 0, stream>>>(Qb, Kb, Vt, out);
}

// Round 2
// 256.537 us; speedup vs baseline: 2.0680x; 2.0680x over previous
//
#include <hip/hip_runtime.h>
#include <hip/hip_bf16.h>

#define BATCH 4
#define SEQ   4096
#define DIN   512
#define DOUT  64

typedef __attribute__((ext_vector_type(4))) float f32x4;
typedef __attribute__((ext_vector_type(8))) short bf16x8;   // 8 bf16 = 4 VGPRs

__device__ __forceinline__ f32x4 mfma16(bf16x8 a, bf16x8 b, f32x4 c) {
    return __builtin_amdgcn_mfma_f32_16x16x32_bf16(a, b, c, 0, 0, 0);
}

// fp32 -> bf16 round-to-nearest-even (finite inputs only)
__device__ __forceinline__ short f2bf(float f) {
    union { float f; unsigned u; } x; x.f = f;
    unsigned r = x.u + 0x7FFFu + ((x.u >> 16) & 1u);
    return (short)(r >> 16);
}

// ---------------------------------------------------------------------------
// W convert+transpose: W[512][64] fp32 -> Wt[64][512] bf16, for 3 matrices.
// Tiny (98K elements); W is L2-resident after first lines. ~2 us.
// ---------------------------------------------------------------------------
__global__ __launch_bounds__(256) void wconv_kernel(
    const float* __restrict__ Wq, const float* __restrict__ Wk,
    const float* __restrict__ Wv, short* __restrict__ Wt)
{
    const int m = blockIdx.y;
    const float* W = (m == 0) ? Wq : (m == 1) ? Wk : Wv;
    const int idx = blockIdx.x * 256 + threadIdx.x;   // 0..32767
    const int n = idx >> 9;
    const int k = idx & 511;
    Wt[m * (DOUT * DIN) + idx] = f2bf(W[k * DOUT + n]);
}

// ---------------------------------------------------------------------------
// QKV projection as bf16 MFMA GEMM: [16384 x 512] x [512 x 64].
// Block: 64 rows; wave: 16 rows x 64 cols (4 n-block accumulators).
// A-frag: X fp32 row-major, 2x float4 load + cvt (A[m=l16][k=quad*8+j]).
// B-frag: Wt bf16 [64][512], contiguous 16B (B[k][n] = Wt[n][k]).
// Output: m=0 -> Qb row-major, m=1 -> Kb row-major, m=2 -> Vt transposed.
// ---------------------------------------------------------------------------
__global__ __launch_bounds__(256) void proj_kernel(
    const float* __restrict__ Xq, const float* __restrict__ Xk, const float* __restrict__ Xv,
    const short* __restrict__ Wt,
    short* __restrict__ Qb, short* __restrict__ Kb, short* __restrict__ Vt)
{
    const int m = blockIdx.y;
    const float* X  = (m == 0) ? Xq : (m == 1) ? Xk : Xv;
    const short* Wm = Wt + m * (DOUT * DIN);

    const int tid  = threadIdx.x;
    const int wv   = tid >> 6;
    const int lane = tid & 63;
    const int quad = lane >> 4;
    const int l16  = lane & 15;
    const long row0 = (long)blockIdx.x * 64 + wv * 16;

    f32x4 acc[4];
    #pragma unroll
    for (int e = 0; e < 4; ++e) acc[e] = (f32x4){0.f, 0.f, 0.f, 0.f};

    const float* xp = X + (row0 + l16) * DIN + quad * 8;

    #pragma unroll 4
    for (int k0 = 0; k0 < DIN; k0 += 32) {
        float4 xa = *(const float4*)(xp + k0);
        float4 xb = *(const float4*)(xp + k0 + 4);
        bf16x8 af;
        af[0] = f2bf(xa.x); af[1] = f2bf(xa.y); af[2] = f2bf(xa.z); af[3] = f2bf(xa.w);
        af[4] = f2bf(xb.x); af[5] = f2bf(xb.y); af[6] = f2bf(xb.z); af[7] = f2bf(xb.w);
        #pragma unroll
        for (int e = 0; e < 4; ++e) {
            bf16x8 bf = *(const bf16x8*)(Wm + (e * 16 + l16) * DIN + k0 + quad * 8);
            acc[e] = mfma16(af, bf, acc[e]);
        }
    }

    if (m < 2) {
        short* O = (m == 0) ? Qb : Kb;
        #pragma unroll
        for (int e = 0; e < 4; ++e)
            #pragma unroll
            for (int r = 0; r < 4; ++r)
                O[(row0 + quad * 4 + r) * DOUT + e * 16 + l16] = f2bf(acc[e][r]);
    } else {
        const long b = row0 >> 12;
        const long s = row0 & (SEQ - 1);
        #pragma unroll
        for (int e = 0; e < 4; ++e)
            #pragma unroll
            for (int r = 0; r < 4; ++r)
                Vt[(b * DOUT + e * 16 + l16) * SEQ + s + quad * 4 + r] = f2bf(acc[e][r]);
    }
}

// ---------------------------------------------------------------------------
// Causal flash attention, bf16 MFMA 16x16x32, KV-split across 4 waves.
// Block = one 16-row q-tile; wave wv handles KV tiles s0 = wv*32, +128, ...
// Partials (m, l, acc) merged through LDS at the end.
// Fragment layouts (verified m89):
//   A: A[m][k], m = lane&15, k = (lane>>4)*8 + j
//   B: B[k][n], n = lane&15, k = (lane>>4)*8 + j
//   C: row = (lane>>4)*4 + reg, col = lane&15
// ---------------------------------------------------------------------------
__global__ __launch_bounds__(256) void flash_kernel(
    const short* __restrict__ Qb, const short* __restrict__ Kb,
    const short* __restrict__ Vt, float* __restrict__ Out)
{
    __shared__ float s_p[4][16][36];    // per-wave P C->A transpose buffer
    __shared__ float s_m[4][16];        // per-wave row max
    __shared__ float s_l[4][16];        // per-wave row sum
    __shared__ float s_acc[4][16][68];  // per-wave O partial (padded stride)

    const int b    = blockIdx.y;
    const int tid  = threadIdx.x;
    const int wv   = tid >> 6;
    const int lane = tid & 63;
    const int quad = lane >> 4;
    const int l16  = lane & 15;
    const int q0   = blockIdx.x * 16;

    const short* Qp = Qb + ((long)b * SEQ + q0 + l16) * DOUT + quad * 8;
    bf16x8 qf0 = *(const bf16x8*)(Qp);        // d = 0..31
    bf16x8 qf1 = *(const bf16x8*)(Qp + 32);   // d = 32..63

    const short* Kbase = Kb + (long)b * SEQ * DOUT;
    const short* Vbase = Vt + (long)b * DOUT * SEQ;

    f32x4 acc[4];
    #pragma unroll
    for (int e = 0; e < 4; ++e) acc[e] = (f32x4){0.f, 0.f, 0.f, 0.f};
    float mrow[4] = {-1e30f, -1e30f, -1e30f, -1e30f};
    float lrow[4] = {0.f, 0.f, 0.f, 0.f};

    const int q_hi = q0 + 15;
    float* lp = &s_p[wv][0][0];

    for (int s0 = wv * 32; s0 <= q_hi; s0 += 128) {
        // ---- scores S = Q K^T for 16 q-rows x 32 keys ----
        f32x4 sc0 = (f32x4){0.f, 0.f, 0.f, 0.f};
        f32x4 sc1 = (f32x4){0.f, 0.f, 0.f, 0.f};
        {
            const short* kp0 = Kbase + (long)(s0 + l16) * DOUT + quad * 8;
            const short* kp1 = Kbase + (long)(s0 + 16 + l16) * DOUT + quad * 8;
            bf16x8 k00 = *(const bf16x8*)(kp0);
            bf16x8 k01 = *(const bf16x8*)(kp0 + 32);
            bf16x8 k10 = *(const bf16x8*)(kp1);
            bf16x8 k11 = *(const bf16x8*)(kp1 + 32);
            sc0 = mfma16(qf0, k00, sc0);
            sc0 = mfma16(qf1, k01, sc0);
            sc1 = mfma16(qf0, k10, sc1);
            sc1 = mfma16(qf1, k11, sc1);
        }

        // ---- scale + causal mask (-1e30, never -inf => no NaN) ----
        #pragma unroll
        for (int r = 0; r < 4; ++r) {
            const int rowg = q0 + quad * 4 + r;
            sc0[r] = ((s0 + l16)      <= rowg) ? sc0[r] * 0.125f : -1e30f;
            sc1[r] = ((s0 + 16 + l16) <= rowg) ? sc1[r] * 0.125f : -1e30f;
        }

        // ---- online softmax within 16-lane groups ----
        float tm[4], alpha[4], p0[4], p1[4], rs[4];
        #pragma unroll
        for (int r = 0; r < 4; ++r) tm[r] = fmaxf(sc0[r], sc1[r]);
        #pragma unroll
        for (int off = 1; off < 16; off <<= 1) {
            #pragma unroll
            for (int r = 0; r < 4; ++r)
                tm[r] = fmaxf(tm[r], __shfl_xor(tm[r], off, 64));
        }
        #pragma unroll
        for (int r = 0; r < 4; ++r) {
            const float mn = fmaxf(mrow[r], tm[r]);
            alpha[r] = __expf(mrow[r] - mn);
            mrow[r]  = mn;
            p0[r] = __expf(sc0[r] - mn);
            p1[r] = __expf(sc1[r] - mn);
            rs[r] = p0[r] + p1[r];
        }
        #pragma unroll
        for (int off = 1; off < 16; off <<= 1) {
            #pragma unroll
            for (int r = 0; r < 4; ++r)
                rs[r] += __shfl_xor(rs[r], off, 64);
        }
        #pragma unroll
        for (int r = 0; r < 4; ++r) lrow[r] = lrow[r] * alpha[r] + rs[r];
        #pragma unroll
        for (int e = 0; e < 4; ++e)
            #pragma unroll
            for (int r = 0; r < 4; ++r) acc[e][r] *= alpha[r];

        // ---- P: C layout -> A layout via per-wave LDS (intra-wave fences) ----
        __asm__ volatile("s_waitcnt lgkmcnt(0)" ::: "memory");  // WAR vs prev iter
        #pragma unroll
        for (int r = 0; r < 4; ++r) {
            lp[(quad * 4 + r) * 36 + l16]      = p0[r];
            lp[(quad * 4 + r) * 36 + 16 + l16] = p1[r];
        }
        __asm__ volatile("s_waitcnt lgkmcnt(0)" ::: "memory");  // RAW
        const float* rp = lp + l16 * 36 + quad * 8;
        float4 pa = *(const float4*)(rp);
        float4 pb = *(const float4*)(rp + 4);
        bf16x8 pf;
        pf[0] = f2bf(pa.x); pf[1] = f2bf(pa.y); pf[2] = f2bf(pa.z); pf[3] = f2bf(pa.w);
        pf[4] = f2bf(pb.x); pf[5] = f2bf(pb.y); pf[6] = f2bf(pb.z); pf[7] = f2bf(pb.w);

        // ---- O += P V  (B-frag = contiguous 16B from Vt) ----
        #pragma unroll
        for (int e = 0; e < 4; ++e) {
            const short* vp = Vbase + (long)(e * 16 + l16) * SEQ + s0 + quad * 8;
            bf16x8 vf = *(const bf16x8*)(vp);
            acc[e] = mfma16(pf, vf, acc[e]);
        }
    }

    // ---- publish per-wave partials ----
    if (l16 == 0) {
        #pragma unroll
        for (int r = 0; r < 4; ++r) {
            s_m[wv][quad * 4 + r] = mrow[r];
            s_l[wv][quad * 4 + r] = lrow[r];
        }
    }
    #pragma unroll
    for (int e = 0; e < 4; ++e)
        #pragma unroll
        for (int r = 0; r < 4; ++r)
            s_acc[wv][quad * 4 + r][e * 16 + l16] = acc[e][r];
    __syncthreads();

    // ---- merge 4 partials: thread = (rowgroup, col) ----
    const int col = tid & 63;
    const int r0  = (tid >> 6) * 4;
    float* outp = Out + ((long)b * SEQ + q0) * DOUT;
    #pragma unroll
    for (int r = 0; r < 4; ++r) {
        const int row = r0 + r;
        const float m0 = s_m[0][row], m1 = s_m[1][row];
        const float m2 = s_m[2][row], m3 = s_m[3][row];
        const float mM = fmaxf(fmaxf(m0, m1), fmaxf(m2, m3));
        const float a0 = __expf(m0 - mM), a1 = __expf(m1 - mM);
        const float a2 = __expf(m2 - mM), a3 = __expf(m3 - mM);
        const float li = a0 * s_l[0][row] + a1 * s_l[1][row]
                       + a2 * s_l[2][row] + a3 * s_l[3][row];
        const float o  = a0 * s_acc[0][row][col] + a1 * s_acc[1][row][col]
                       + a2 * s_acc[2][row][col] + a3 * s_acc[3][row][col];
        outp[row * DOUT + col] = o / li;
    }
}

extern "C" void kernel_launch(void* const* d_in, const int* in_sizes, int n_in,
                              void* d_out, int out_size, void* d_ws, size_t ws_size,
                              hipStream_t stream) {
    const float* key_in   = (const float*)d_in[0];
    const float* value_in = (const float*)d_in[1];
    const float* query_in = (const float*)d_in[2];
    const float* Wq = (const float*)d_in[3];
    const float* Wk = (const float*)d_in[4];
    const float* Wv = (const float*)d_in[5];
    float* out = (float*)d_out;

    short* Qb = (short*)d_ws;                          // 2 MB bf16 [B][S][64]
    short* Kb = Qb + (long)BATCH * SEQ * DOUT;         // 2 MB bf16 [B][S][64]
    short* Vt = Kb + (long)BATCH * SEQ * DOUT;         // 2 MB bf16 [B][64][S]
    short* Wt = Vt + (long)BATCH * SEQ * DOUT;         // 192 KB bf16 [3][64][512]

    dim3 wgrid((DOUT * DIN) / 256, 3);
    wconv_kernel<<<wgrid, 256, 0, stream>>>(Wq, Wk, Wv, Wt);

    dim3 pgrid(BATCH * SEQ / 64, 3);
    proj_kernel<<<pgrid, 256, 0, stream>>>(query_in, key_in, value_in,
                                           Wt, Qb, Kb, Vt);

    dim3 fgrid(SEQ / 16, BATCH);
    flash_kernel<<<fgrid, 256, 0, stream>>>(Qb, Kb, Vt, out);
}